// Round 11
// baseline (158.224 us; speedup 1.0000x reference)
//
#include <hip/hip_runtime.h>

typedef __attribute__((ext_vector_type(8))) short bf16x8;
typedef __attribute__((ext_vector_type(4))) float f32x4;
typedef unsigned int u32;

#define TOK 16384
#define DIM 128
#define SEQ 2048

__device__ inline unsigned short f2bf(float f){
  union { float f; u32 u; } v; v.f = f;
  u32 r = v.u + 0x7fffu + ((v.u >> 16) & 1u);
  return (unsigned short)(r >> 16);
}
__device__ inline float bf2f(unsigned short u){
  union { u32 u; float f; } v; v.u = ((u32)u) << 16;
  return v.f;
}

__device__ inline void gld16(const void* g, const void* l){
  __builtin_amdgcn_global_load_lds((const __attribute__((address_space(1))) void*)g,
                                   (__attribute__((address_space(3))) void*)l, 16, 0, 0);
}

template<int CTRL>
__device__ inline float dppf(float x){
  return __builtin_bit_cast(float,
    __builtin_amdgcn_update_dpp(0, __builtin_bit_cast(int, x), CTRL, 0xF, 0xF, true));
}
__device__ inline float rmax16(float x){
  x = fmaxf(x, dppf<0xB1>(x));
  x = fmaxf(x, dppf<0x4E>(x));
  x = fmaxf(x, dppf<0x124>(x));
  x = fmaxf(x, dppf<0x128>(x));
  return x;
}
__device__ inline float rsum16(float x){
  x += dppf<0xB1>(x);
  x += dppf<0x4E>(x);
  x += dppf<0x124>(x);
  x += dppf<0x128>(x);
  return x;
}

// ---------------- kernel 0: weights -> bf16, transposed [out][in], chunk-swizzled ----------------
__global__ __launch_bounds__(256) void prep_w(const float* __restrict__ W1, const float* __restrict__ Wq,
                                              const float* __restrict__ Wk, const float* __restrict__ Wv,
                                              unsigned short* __restrict__ wt){
  int w = blockIdx.x >> 2, qtr = blockIdx.x & 3;
  const float* W = (w==0)?W1:((w==1)?Wq:((w==2)?Wk:Wv));
  unsigned short* dst = wt + w*16384;
  int c = threadIdx.x & 127;
  int khalf = threadIdx.x >> 7;
  int kbase = qtr*32 + khalf*16;
  unsigned short tmp[16];
  #pragma unroll
  for (int i=0;i<16;i++) tmp[i] = f2bf(W[(kbase+i)*128 + c]);
  #pragma unroll
  for (int h=0;h<2;h++){
    int k0 = kbase + h*8;
    int chunk = (k0 >> 3) ^ (c & 7);
    bf16x8 pk;
    #pragma unroll
    for (int j=0;j<8;j++) pk[j] = (short)tmp[h*8+j];
    *reinterpret_cast<bf16x8*>(dst + c*128 + chunk*8) = pk;
  }
}

// ---------------- kernel 1: res = q@W1 ; qh/kh/vh = res@{Wq,Wk,Wv}  (512 thr, 8 waves) ----------------
__global__ __launch_bounds__(512,2) void proj(const float* __restrict__ q, const unsigned short* __restrict__ wt,
                                              float* __restrict__ out,
                                              unsigned short* __restrict__ qh, unsigned short* __restrict__ kh,
                                              unsigned short* __restrict__ vht){
  __shared__ unsigned short sW[4*128*128];   // 128 KB
  __shared__ unsigned short sX[64*128];      // 16 KB
  unsigned short* sVh = sW;                  // alias W1 region (dead after GEMM1)

  int tid = threadIdx.x;
  int lane = tid & 63, wid = tid >> 6;       // 8 waves
  int l15 = lane & 15, lg = lane >> 4;
  int wr = wid & 3;                          // row-wave: rows wr*16..+16
  int chh = wid >> 2;                        // col half: cols chh*64..+64
  int rowbase = blockIdx.x * 64;

  #pragma unroll
  for (int p=0;p<16;p++)
    gld16((const char*)wt + p*8192 + tid*16, (const char*)sW + p*8192 + wid*1024);

  { // q tile -> bf16, chunk-swizzled rows
    int r = tid >> 3, cg = tid & 7;
    const float* qp = q + (size_t)(rowbase + r)*128 + cg*16;
    #pragma unroll
    for (int c8=0;c8<2;c8++){
      bf16x8 pk;
      #pragma unroll
      for (int j=0;j<8;j++) pk[j] = (short)f2bf(qp[c8*8 + j]);
      int chunk = (cg*2 + c8) ^ (r & 7);
      *reinterpret_cast<bf16x8*>(sX + r*128 + chunk*8) = pk;
    }
  }
  __syncthreads();

  auto gemm = [&](const unsigned short* sA, const unsigned short* sB, f32x4 acc[4]){
    #pragma unroll
    for (int ct=0;ct<4;ct++) acc[ct] = (f32x4){0.f,0.f,0.f,0.f};
    #pragma unroll
    for (int kt=0;kt<4;kt++){
      int ar = wr*16 + l15;
      bf16x8 a = *reinterpret_cast<const bf16x8*>(sA + ar*128 + (((kt*4+lg) ^ (ar&7))*8));
      #pragma unroll
      for (int ct=0;ct<4;ct++){
        int cc = chh*64 + ct*16 + l15;
        bf16x8 bb = *reinterpret_cast<const bf16x8*>(sB + cc*128 + (((kt*4+lg) ^ (cc&7))*8));
        acc[ct] = __builtin_amdgcn_mfma_f32_16x16x32_bf16(a, bb, acc[ct], 0, 0, 0);
      }
    }
  };

  f32x4 acc[4];

  // GEMM1: res
  gemm(sX, sW, acc);
  #pragma unroll
  for (int ct=0;ct<4;ct++)
    #pragma unroll
    for (int i=0;i<4;i++){
      int r = wr*16 + lg*4 + i, c = chh*64 + ct*16 + l15;
      int rg = rowbase + r;
      float v = acc[ct][i];
      out[rg*256 + 128 + c] = v;
      out[TOK*256 + rg*128 + c] = v;
    }
  __syncthreads();
  #pragma unroll
  for (int ct=0;ct<4;ct++)
    #pragma unroll
    for (int i=0;i<4;i++){
      int r = wr*16 + lg*4 + i, c = chh*64 + ct*16 + l15;
      sX[r*128 + (((c>>3) ^ (r&7))*8) + (c&7)] = f2bf(acc[ct][i]);
    }
  __syncthreads();

  // GEMM2: qh, fold (1/sqrt(128)) * log2(e)
  gemm(sX, sW + 16384, acc);
  const float SCALE = 0.12751742f;
  #pragma unroll
  for (int ct=0;ct<4;ct++)
    #pragma unroll
    for (int i=0;i<4;i++){
      int r = wr*16 + lg*4 + i, c = chh*64 + ct*16 + l15;
      qh[(rowbase + r)*128 + c] = f2bf(acc[ct][i]*SCALE);
    }

  // GEMM3: kh, plain row-major [tok][feat] (no LDS staging downstream -> no swizzle)
  gemm(sX, sW + 2*16384, acc);
  #pragma unroll
  for (int ct=0;ct<4;ct++)
    #pragma unroll
    for (int i=0;i<4;i++){
      int r = wr*16 + lg*4 + i, c = chh*64 + ct*16 + l15;
      kh[(rowbase + r)*128 + c] = f2bf(acc[ct][i]);
    }

  // GEMM4: vh -> transposed [b][feat][n]
  gemm(sX, sW + 3*16384, acc);
  __syncthreads();
  #pragma unroll
  for (int ct=0;ct<4;ct++)
    #pragma unroll
    for (int i=0;i<4;i++){
      int r = wr*16 + lg*4 + i, c = chh*64 + ct*16 + l15;
      sVh[r*130 + c] = f2bf(acc[ct][i]);
    }
  __syncthreads();
  {
    int bb = rowbase >> 11;
    int n0 = rowbase & 2047;
    #pragma unroll
    for (int it=0; it<2; ++it){
      int idx = tid + it*512;
      int f = idx >> 3, ch = idx & 7;
      bf16x8 pk;
      #pragma unroll
      for (int j=0;j<8;j++) pk[j] = (short)sVh[(ch*8+j)*130 + f];
      int ci = (n0 >> 3) + ch;
      *reinterpret_cast<bf16x8*>(vht + bb*(DIM*SEQ) + f*SEQ + ci*8) = pk;
    }
  }
}

// ---------------- kernel 2: flash attention, ZERO barriers, wave-independent, K/V from L2 ----------------
__global__ __launch_bounds__(256,3) void attn(const unsigned short* __restrict__ qh,
                                              const unsigned short* __restrict__ kh,
                                              const unsigned short* __restrict__ vht,
                                              const float* __restrict__ adj,
                                              unsigned short* __restrict__ po,
                                              float* __restrict__ pml){
  __shared__ unsigned short sP[4][16*40];    // 5 KB, wave-private quadrants

  const int tid = threadIdx.x;
  const int lane = tid & 63, wid = tid >> 6;
  const int l15 = lane & 15, lg = lane >> 4;
  const int bid = blockIdx.x;                // 1024 = (4 quarter x 32 qblk) x 8 batch
  const int b = bid & 7;                     // batch -> XCD affinity (round-robin %8)
  const int qq = bid >> 3;                   // 0..127
  const int quarter = qq >> 5;
  const int qbase = (qq & 31) * 64;          // block covers 64 q-rows; wave owns 16
  const int wrow = wid * 16;
  const int tokbase = b*SEQ + qbase;
  const int kvbase = quarter * 512;          // 16 tiles of 32
  const unsigned short* khb = kh + (size_t)(b*SEQ + kvbase)*128;
  const unsigned short* vhb = vht + (size_t)b*DIM*SEQ + kvbase;
  const float* adjl = adj + ((size_t)(b*SEQ + qbase + wrow + lg*4))*SEQ + kvbase + l15;

  // Q fragments (scale+log2e pre-folded)
  bf16x8 qf[4];
  {
    const unsigned short* qp = qh + (size_t)(tokbase + wrow + l15)*128;
    #pragma unroll
    for (int kt=0;kt<4;kt++) qf[kt] = *reinterpret_cast<const bf16x8*>(qp + kt*32 + lg*8);
  }

  f32x4 o[8];
  #pragma unroll
  for (int ct=0;ct<8;ct++) o[ct] = (f32x4){0.f,0.f,0.f,0.f};
  float mrow[4], lrow[4];
  #pragma unroll
  for (int i=0;i<4;i++){ mrow[i] = -3e38f; lrow[i] = 0.f; }

  auto ldadj = [&](int tt, float* a){
    const float* ap = adjl + tt*32;
    #pragma unroll
    for (int i=0;i<4;i++)
      #pragma unroll
      for (int ct=0;ct<2;ct++)
        a[i*2+ct] = __builtin_nontemporal_load(ap + (size_t)i*SEQ + ct*16);
  };

  auto body = [&](int tt, const float* a){
    // S = Q K^T : K fragments straight from L2 (no LDS, no barrier)
    const unsigned short* kt0 = khb + (size_t)tt*32*128;
    f32x4 s[2];
    #pragma unroll
    for (int ct=0;ct<2;ct++) s[ct] = (f32x4){0.f,0.f,0.f,0.f};
    #pragma unroll
    for (int kt=0;kt<4;kt++){
      #pragma unroll
      for (int ct=0;ct<2;ct++){
        bf16x8 kf = *reinterpret_cast<const bf16x8*>(kt0 + (ct*16+l15)*128 + (kt*4+lg)*8);
        s[ct] = __builtin_amdgcn_mfma_f32_16x16x32_bf16(qf[kt], kf, s[ct], 0,0,0);
      }
    }
    // mask from registers
    #pragma unroll
    for (int i=0;i<4;i++)
      #pragma unroll
      for (int ct=0;ct<2;ct++)
        if (a[i*2+ct] == 0.f) s[ct][i] = -1e9f;
    // online softmax (exp2 domain), defer-max THR=8
    #pragma unroll
    for (int i=0;i<4;i++){
      float pm = fmaxf(s[0][i], s[1][i]);
      pm = rmax16(pm);
      if (__any(pm > mrow[i] + 8.f)){
        float nm = fmaxf(mrow[i], pm);
        float scv = exp2f(mrow[i] - nm);
        mrow[i] = nm;
        lrow[i] *= scv;
        #pragma unroll
        for (int ct=0;ct<8;ct++) o[ct][i] *= scv;
      }
      float p0 = exp2f(s[0][i] - mrow[i]);
      float p1 = exp2f(s[1][i] - mrow[i]);
      s[0][i]=p0; s[1][i]=p1;
      lrow[i] += rsum16(p0+p1);
    }
    // P -> wave-private LDS (C-layout -> A-layout); lgkmcnt-only, no barrier
    unsigned short* Pw = sP[wid];
    #pragma unroll
    for (int ct=0;ct<2;ct++)
      #pragma unroll
      for (int i=0;i<4;i++)
        Pw[(lg*4+i)*40 + ct*16 + l15] = f2bf(s[ct][i]);
    bf16x8 pa = *reinterpret_cast<const bf16x8*>(Pw + l15*40 + lg*8);
    // O += P V : V fragments straight from L2
    #pragma unroll
    for (int ct=0;ct<8;ct++){
      bf16x8 vf = *reinterpret_cast<const bf16x8*>(vhb + (size_t)(ct*16+l15)*SEQ + tt*32 + lg*8);
      o[ct] = __builtin_amdgcn_mfma_f32_16x16x32_bf16(pa, vf, o[ct], 0,0,0);
    }
  };

  float afA[8], afB[8];
  ldadj(0, afA);

  #pragma unroll 1
  for (int t=0; t<16; t+=2){
    ldadj(t+1, afB);
    body(t, afA);
    if (t+2 < 16) ldadj(t+2, afA);
    body(t+1, afB);
  }

  // write unnormalized partials + (m,l)
  #pragma unroll
  for (int ct=0;ct<8;ct++)
    #pragma unroll
    for (int i=0;i<4;i++){
      int row = tokbase + wrow + lg*4 + i;
      po[(size_t)(quarter*TOK + row)*128 + ct*16 + l15] = f2bf(o[ct][i]);
    }
  if (l15 == 0){
    #pragma unroll
    for (int i=0;i<4;i++){
      int row = tokbase + wrow + lg*4 + i;
      pml[(size_t)row*8 + quarter*2 + 0] = mrow[i];
      pml[(size_t)row*8 + quarter*2 + 1] = lrow[i];
    }
  }
}

// ---------------- kernel 3: merge 4 split-KV partials (512 blocks, 32 rows each) ----------------
__global__ __launch_bounds__(256) void merge(const unsigned short* __restrict__ po,
                                             const float* __restrict__ pml,
                                             float* __restrict__ out){
  const int mblk = blockIdx.x;               // 512 = 64 qblk x 8 batch
  const int b = mblk & 7, q32 = mblk >> 3;   // same XCD as producers
  const int tokbase = b*SEQ + q32*32;
  const int tid = threadIdx.x;
  const int row = tokbase + (tid >> 3);
  const int c0 = (tid & 7) * 16;

  f32x4 ml0 = *reinterpret_cast<const f32x4*>(pml + (size_t)row*8);
  f32x4 ml1 = *reinterpret_cast<const f32x4*>(pml + (size_t)row*8 + 4);
  float m[4] = {ml0[0], ml0[2], ml1[0], ml1[2]};
  float l[4] = {ml0[1], ml0[3], ml1[1], ml1[3]};
  float M = fmaxf(fmaxf(m[0], m[1]), fmaxf(m[2], m[3]));
  float a[4], L = 0.f;
  #pragma unroll
  for (int qq=0;qq<4;qq++){ a[qq] = exp2f(m[qq] - M); L += a[qq]*l[qq]; }
  float inv = 1.f / L;
  #pragma unroll
  for (int qq=0;qq<4;qq++) a[qq] *= inv;

  float r[16];
  #pragma unroll
  for (int j=0;j<16;j++) r[j] = 0.f;
  #pragma unroll
  for (int qq=0;qq<4;qq++){
    const unsigned short* pp = po + (size_t)(qq*TOK + row)*128 + c0;
    bf16x8 v0 = *reinterpret_cast<const bf16x8*>(pp);
    bf16x8 v1 = *reinterpret_cast<const bf16x8*>(pp + 8);
    #pragma unroll
    for (int j=0;j<8;j++){
      r[j]   += bf2f((unsigned short)v0[j]) * a[qq];
      r[8+j] += bf2f((unsigned short)v1[j]) * a[qq];
    }
  }
  float* op = out + (size_t)row*256 + c0;
  #pragma unroll
  for (int k=0;k<4;k++){
    float4 rv = {r[k*4+0], r[k*4+1], r[k*4+2], r[k*4+3]};
    *reinterpret_cast<float4*>(op + k*4) = rv;
  }
}

extern "C" void kernel_launch(void* const* d_in, const int* in_sizes, int n_in,
                              void* d_out, int out_size, void* d_ws, size_t ws_size,
                              hipStream_t stream){
  (void)in_sizes; (void)n_in; (void)out_size; (void)ws_size;
  const float* q   = (const float*)d_in[0];
  const float* adj = (const float*)d_in[3];
  const float* W1  = (const float*)d_in[4];
  const float* Wq  = (const float*)d_in[5];
  const float* Wk  = (const float*)d_in[6];
  const float* Wv  = (const float*)d_in[7];
  float* out = (float*)d_out;

  unsigned short* qh = (unsigned short*)d_ws;        // 4 MB
  unsigned short* kh = qh + (size_t)TOK*DIM;         // 4 MB (plain row-major)
  unsigned short* vh = kh + (size_t)TOK*DIM;         // 4 MB (transposed per batch)
  unsigned short* wt = vh + (size_t)TOK*DIM;         // 128 KB
  unsigned short* po = wt + 4*128*128;               // 16.8 MB (4 x bf16 partial O)
  float*          pml = (float*)(po + (size_t)4*TOK*DIM);  // 512 KB

  prep_w<<<16,   256, 0, stream>>>(W1, Wq, Wk, Wv, wt);
  proj  <<<256,  512, 0, stream>>>(q, wt, out, qh, kh, vh);
  attn  <<<1024, 256, 0, stream>>>(qh, kh, vh, adj, po, pml);
  merge <<<512,  256, 0, stream>>>(po, pml, out);
}

// Round 12
// 63.720 us; speedup vs baseline: 2.4831x; 2.4831x over previous
//
#include <hip/hip_runtime.h>

typedef __attribute__((ext_vector_type(8)))  short bf16x8;
typedef __attribute__((ext_vector_type(4)))  float f32x4;
typedef __attribute__((ext_vector_type(16))) float f32x16;
typedef unsigned int u32;
typedef __attribute__((ext_vector_type(4)))  unsigned int u32x4;

#define TOK 16384
#define DIM 128
#define SEQ 2048

__device__ inline unsigned short f2bf(float f){
  union { float f; u32 u; } v; v.f = f;
  u32 r = v.u + 0x7fffu + ((v.u >> 16) & 1u);
  return (unsigned short)(r >> 16);
}
__device__ inline float bf2f(unsigned short u){
  union { u32 u; float f; } v; v.u = ((u32)u) << 16;
  return v.f;
}
__device__ inline u32 pk2(float a, float b){
  return (u32)f2bf(a) | ((u32)f2bf(b) << 16);
}

__device__ inline void gld16(const void* g, const void* l){
  __builtin_amdgcn_global_load_lds((const __attribute__((address_space(1))) void*)g,
                                   (__attribute__((address_space(3))) void*)l, 16, 0, 0);
}

// ---------------- kernel 0: weights -> bf16, transposed [out][in], chunk-swizzled ----------------
__global__ __launch_bounds__(256) void prep_w(const float* __restrict__ W1, const float* __restrict__ Wq,
                                              const float* __restrict__ Wk, const float* __restrict__ Wv,
                                              unsigned short* __restrict__ wt){
  int w = blockIdx.x >> 2, qtr = blockIdx.x & 3;
  const float* W = (w==0)?W1:((w==1)?Wq:((w==2)?Wk:Wv));
  unsigned short* dst = wt + w*16384;
  int c = threadIdx.x & 127;
  int khalf = threadIdx.x >> 7;
  int kbase = qtr*32 + khalf*16;
  unsigned short tmp[16];
  #pragma unroll
  for (int i=0;i<16;i++) tmp[i] = f2bf(W[(kbase+i)*128 + c]);
  #pragma unroll
  for (int h=0;h<2;h++){
    int k0 = kbase + h*8;
    int chunk = (k0 >> 3) ^ (c & 7);
    bf16x8 pk;
    #pragma unroll
    for (int j=0;j<8;j++) pk[j] = (short)tmp[h*8+j];
    *reinterpret_cast<bf16x8*>(dst + c*128 + chunk*8) = pk;
  }
}

// ---------------- kernel 1: res = q@W1 ; qh/kh/vh = res@{Wq,Wk,Wv}  (512 thr, 8 waves) ----------------
__global__ __launch_bounds__(512,2) void proj(const float* __restrict__ q, const unsigned short* __restrict__ wt,
                                              float* __restrict__ out,
                                              unsigned short* __restrict__ qh, unsigned short* __restrict__ khsw,
                                              unsigned short* __restrict__ vht){
  __shared__ unsigned short sW[4*128*128];
  __shared__ unsigned short sX[64*128];
  unsigned short* sVh = sW;

  int tid = threadIdx.x;
  int lane = tid & 63, wid = tid >> 6;
  int l15 = lane & 15, lg = lane >> 4;
  int wr = wid & 3;
  int chh = wid >> 2;
  int rowbase = blockIdx.x * 64;

  #pragma unroll
  for (int p=0;p<16;p++)
    gld16((const char*)wt + p*8192 + tid*16, (const char*)sW + p*8192 + wid*1024);

  {
    int r = tid >> 3, cg = tid & 7;
    const float* qp = q + (size_t)(rowbase + r)*128 + cg*16;
    #pragma unroll
    for (int c8=0;c8<2;c8++){
      bf16x8 pk;
      #pragma unroll
      for (int j=0;j<8;j++) pk[j] = (short)f2bf(qp[c8*8 + j]);
      int chunk = (cg*2 + c8) ^ (r & 7);
      *reinterpret_cast<bf16x8*>(sX + r*128 + chunk*8) = pk;
    }
  }
  __syncthreads();

  auto gemm = [&](const unsigned short* sA, const unsigned short* sB, f32x4 acc[4]){
    #pragma unroll
    for (int ct=0;ct<4;ct++) acc[ct] = (f32x4){0.f,0.f,0.f,0.f};
    #pragma unroll
    for (int kt=0;kt<4;kt++){
      int ar = wr*16 + l15;
      bf16x8 a = *reinterpret_cast<const bf16x8*>(sA + ar*128 + (((kt*4+lg) ^ (ar&7))*8));
      #pragma unroll
      for (int ct=0;ct<4;ct++){
        int cc = chh*64 + ct*16 + l15;
        bf16x8 bb = *reinterpret_cast<const bf16x8*>(sB + cc*128 + (((kt*4+lg) ^ (cc&7))*8));
        acc[ct] = __builtin_amdgcn_mfma_f32_16x16x32_bf16(a, bb, acc[ct], 0, 0, 0);
      }
    }
  };

  f32x4 acc[4];

  // GEMM1: res
  gemm(sX, sW, acc);
  #pragma unroll
  for (int ct=0;ct<4;ct++)
    #pragma unroll
    for (int i=0;i<4;i++){
      int r = wr*16 + lg*4 + i, c = chh*64 + ct*16 + l15;
      int rg = rowbase + r;
      float v = acc[ct][i];
      out[rg*256 + 128 + c] = v;
      out[TOK*256 + rg*128 + c] = v;
    }
  __syncthreads();
  #pragma unroll
  for (int ct=0;ct<4;ct++)
    #pragma unroll
    for (int i=0;i<4;i++){
      int r = wr*16 + lg*4 + i, c = chh*64 + ct*16 + l15;
      sX[r*128 + (((c>>3) ^ (r&7))*8) + (c&7)] = f2bf(acc[ct][i]);
    }
  __syncthreads();

  // GEMM2: qh, fold (1/sqrt(128)) * log2(e)
  gemm(sX, sW + 16384, acc);
  const float SCALE = 0.12751742f;
  #pragma unroll
  for (int ct=0;ct<4;ct++)
    #pragma unroll
    for (int i=0;i<4;i++){
      int r = wr*16 + lg*4 + i, c = chh*64 + ct*16 + l15;
      qh[(rowbase + r)*128 + c] = f2bf(acc[ct][i]*SCALE);
    }

  // GEMM3: kh, row-chunk-swizzled
  gemm(sX, sW + 2*16384, acc);
  #pragma unroll
  for (int ct=0;ct<4;ct++)
    #pragma unroll
    for (int i=0;i<4;i++){
      int r = wr*16 + lg*4 + i, c = chh*64 + ct*16 + l15;
      int rg = rowbase + r;
      khsw[rg*128 + (c ^ ((rg&7)<<3))] = f2bf(acc[ct][i]);
    }

  // GEMM4: vh -> transposed [b][feat][n]
  gemm(sX, sW + 3*16384, acc);
  __syncthreads();
  #pragma unroll
  for (int ct=0;ct<4;ct++)
    #pragma unroll
    for (int i=0;i<4;i++){
      int r = wr*16 + lg*4 + i, c = chh*64 + ct*16 + l15;
      sVh[r*130 + c] = f2bf(acc[ct][i]);
    }
  __syncthreads();
  {
    int bb = rowbase >> 11;
    int n0 = rowbase & 2047;
    #pragma unroll
    for (int it=0; it<2; ++it){
      int idx = tid + it*512;
      int f = idx >> 3, ch = idx & 7;
      bf16x8 pk;
      #pragma unroll
      for (int j=0;j<8;j++) pk[j] = (short)sVh[(ch*8+j)*130 + f];
      int ci = (n0 >> 3) + ch;
      *reinterpret_cast<bf16x8*>(vht + bb*(DIM*SEQ) + f*SEQ + ci*8) = pk;
    }
  }
}

// ---------------- kernel 2: flash attention, swapped-QK^T 32x32, in-register softmax ----------------
__global__ __launch_bounds__(256,2) void attn(const unsigned short* __restrict__ qh,
                                              const unsigned short* __restrict__ khsw,
                                              const unsigned short* __restrict__ vht,
                                              const float* __restrict__ adj,
                                              unsigned short* __restrict__ po,
                                              float* __restrict__ pml){
  __shared__ char smem[65536];
  unsigned short* sKb = (unsigned short*)smem;            // 2 x [32 kv][128 feat], 8 KB each
  unsigned short* sVb = (unsigned short*)(smem + 16384);  // 2 x [128 feat][32 kv], 8 KB each
  float*          sAb = (float*)(smem + 32768);           // 2 x [128 q][32 kv] f32, 16 KB each

  const int tid  = threadIdx.x;
  const int lane = tid & 63, wid = tid >> 6;
  const int l31  = lane & 31, hl = lane >> 5;
  const int bid  = blockIdx.x;               // 512 = 4 quarter x 16 qblk x 8 batch
  const int quarter = bid >> 7;
  const int b    = bid & 7;                  // batch -> XCD affinity
  const int qblk = (bid >> 3) & 15;
  const int qbase = qblk * 128;              // block covers 128 q-rows
  const int tokbase = b*SEQ + qbase;
  const int kvbase  = quarter * 512;         // 16 tiles of 32
  const int wrow = wid * 32;                 // wave's 32 q-rows
  const unsigned short* vhb = vht + (size_t)b*DIM*SEQ;

  // Q as B-operand fragments (loaded once): qf[c] = Q[wrow+l31][c*16 + hl*8 .. +7]
  bf16x8 qf[8];
  {
    const unsigned short* qp = qh + (size_t)(tokbase + wrow + l31)*128 + hl*8;
    #pragma unroll
    for (int c=0;c<8;c++) qf[c] = *reinterpret_cast<const bf16x8*>(qp + c*16);
  }

  f32x16 o0, o1, o2, o3;
  #pragma unroll
  for (int r=0;r<16;r++){ o0[r]=0.f; o1[r]=0.f; o2[r]=0.f; o3[r]=0.f; }
  float mrow = -3e38f, lrow = 0.f;

  auto stage = [&](int tt, int db){
    const char* kb = (const char*)(khsw + (size_t)(b*SEQ + kvbase + tt*32)*128);
    unsigned short* sK = sKb + db*4096;
    unsigned short* sV = sVb + db*4096;
    float*          sA = sAb + db*4096;
    #pragma unroll
    for (int p=0;p<2;p++)
      gld16(kb + p*4096 + tid*16, (const char*)sK + p*4096 + wid*1024);
    #pragma unroll
    for (int p=0;p<2;p++){
      int u = p*256 + tid;
      int ff = u >> 2, cp = u & 3;
      gld16(vhb + (size_t)ff*SEQ + kvbase + tt*32 + ((cp ^ ((ff>>1)&3))*8),
            (const char*)sV + p*4096 + wid*1024);
    }
    #pragma unroll
    for (int p=0;p<4;p++){
      int u = p*256 + tid;
      int qq = u >> 3, cp = u & 7;    // q-row 0..127, 16B chunk 0..7 (XOR pre-swizzled source)
      gld16(adj + ((size_t)(b*SEQ + qbase + qq))*SEQ + kvbase + tt*32 + ((cp ^ (qq&7))<<2),
            (const char*)sA + p*4096 + wid*1024);
    }
  };

  auto body = [&](int db){
    const unsigned short* sK = sKb + db*4096;
    const unsigned short* sV = sVb + db*4096;
    const float*          sA = sAb + db*4096;
    const int qrow = wrow + l31;             // block-local q row

    // adj for this lane's 16 cells: reg r -> kv = (r&3) + 8*(r>>2) + 4*hl
    f32x4 av[4];
    #pragma unroll
    for (int g=0;g<4;g++)
      av[g] = *reinterpret_cast<const f32x4*>(sA + qrow*32 + (((2*g+hl) ^ (qrow&7))<<2));

    // S^T[kv][q] = K(32x128) · Q^T : lane col = q = l31, reg -> kv
    f32x16 s;
    #pragma unroll
    for (int r=0;r<16;r++) s[r] = 0.f;
    #pragma unroll
    for (int c=0;c<8;c++){
      bf16x8 kf = *reinterpret_cast<const bf16x8*>(sK + l31*128 + (((2*c+hl) ^ (l31&7))*8));
      s = __builtin_amdgcn_mfma_f32_32x32x16_bf16(kf, qf[c], s, 0, 0, 0);
    }

    // mask (cell-matched: av[r>>2][r&3] is adj[q][kv(r)])
    #pragma unroll
    for (int r=0;r<16;r++)
      if (av[r>>2][r&3] == 0.f) s[r] = -1e9f;

    // in-register online softmax (exp2 domain, defer-max THR=8)
    float pm = s[0];
    #pragma unroll
    for (int r=1;r<16;r++) pm = fmaxf(pm, s[r]);
    pm = fmaxf(pm, __shfl_xor(pm, 32));
    if (__any(pm > mrow + 8.f)){
      float nm = fmaxf(mrow, pm);
      float scv = exp2f(mrow - nm);
      mrow = nm; lrow *= scv;
      #pragma unroll
      for (int r=0;r<16;r++){ o0[r]*=scv; o1[r]*=scv; o2[r]*=scv; o3[r]*=scv; }
    }
    #pragma unroll
    for (int r=0;r<16;r++) s[r] = exp2f(s[r] - mrow);
    float ls = 0.f;
    #pragma unroll
    for (int r=0;r<16;r++) ls += s[r];
    ls += __shfl_xor(ls, 32);
    lrow += ls;

    // pack P -> bf16 u32 pairs; exchange halves (lane <-> lane+32)
    u32 u[8], x[8];
    #pragma unroll
    for (int g=0;g<4;g++){
      u[2*g]   = pk2(s[4*g],   s[4*g+1]);
      u[2*g+1] = pk2(s[4*g+2], s[4*g+3]);
    }
    #pragma unroll
    for (int j=0;j<8;j++) x[j] = (u32)__shfl_xor((int)u[j], 32);

    // B-frag(h): k = kv = 16h + 8*hl + e  (e=0..7)
    bf16x8 pb[2];
    #pragma unroll
    for (int h=0;h<2;h++){
      u32 a0 = hl ? x[4*h+2] : u[4*h+0];
      u32 a1 = hl ? x[4*h+3] : u[4*h+1];
      u32 a2 = hl ? u[4*h+2] : x[4*h+0];
      u32 a3 = hl ? u[4*h+3] : x[4*h+1];
      pb[h] = __builtin_bit_cast(bf16x8, (u32x4){a0,a1,a2,a3});
    }

    // O^T[d][q] += V^T(128xkv) · P^T(kv x 32q)
    #pragma unroll
    for (int h=0;h<2;h++){
      const int cw = 2*h + hl;
      { int ff = 0*32 + l31;
        bf16x8 vf = *reinterpret_cast<const bf16x8*>(sV + ff*32 + ((cw ^ ((ff>>1)&3))*8));
        o0 = __builtin_amdgcn_mfma_f32_32x32x16_bf16(vf, pb[h], o0, 0,0,0); }
      { int ff = 1*32 + l31;
        bf16x8 vf = *reinterpret_cast<const bf16x8*>(sV + ff*32 + ((cw ^ ((ff>>1)&3))*8));
        o1 = __builtin_amdgcn_mfma_f32_32x32x16_bf16(vf, pb[h], o1, 0,0,0); }
      { int ff = 2*32 + l31;
        bf16x8 vf = *reinterpret_cast<const bf16x8*>(sV + ff*32 + ((cw ^ ((ff>>1)&3))*8));
        o2 = __builtin_amdgcn_mfma_f32_32x32x16_bf16(vf, pb[h], o2, 0,0,0); }
      { int ff = 3*32 + l31;
        bf16x8 vf = *reinterpret_cast<const bf16x8*>(sV + ff*32 + ((cw ^ ((ff>>1)&3))*8));
        o3 = __builtin_amdgcn_mfma_f32_32x32x16_bf16(vf, pb[h], o3, 0,0,0); }
    }
  };

  stage(0, 0);
  __syncthreads();
  #pragma unroll 1
  for (int t=0; t<16; ++t){
    if (t+1 < 16) stage(t+1, (t+1)&1);
    body(t & 1);
    __syncthreads();
  }

  // (m,l) out
  if (lane < 32){
    int row = tokbase + wrow + lane;
    pml[(size_t)row*8 + quarter*2 + 0] = mrow;
    pml[(size_t)row*8 + quarter*2 + 1] = lrow;
  }

  // epilogue: transpose O^T -> row-major po via per-wave LDS (aliases staging buffers; all
  // waves passed the final barrier so sK/sV/sA are dead)
  float* sT = (float*)smem + wid*1056;       // 32 x 33 floats per wave
  unsigned short* pob = po + (size_t)(quarter*TOK + tokbase + wrow + l31)*128 + hl*16;

  #define EPI(OV, DB) { \
    _Pragma("unroll") \
    for (int r=0;r<16;r++) \
      sT[((r&3) + 8*(r>>2) + 4*hl)*33 + l31] = OV[r]; \
    u32 w[8]; \
    _Pragma("unroll") \
    for (int k=0;k<8;k++){ \
      float v0 = sT[(hl*16 + 2*k)*33 + l31]; \
      float v1 = sT[(hl*16 + 2*k+1)*33 + l31]; \
      w[k] = pk2(v0, v1); \
    } \
    *reinterpret_cast<u32x4*>(pob + DB*32)     = (u32x4){w[0],w[1],w[2],w[3]}; \
    *reinterpret_cast<u32x4*>(pob + DB*32 + 8) = (u32x4){w[4],w[5],w[6],w[7]}; \
  }
  EPI(o0, 0);
  EPI(o1, 1);
  EPI(o2, 2);
  EPI(o3, 3);
  #undef EPI
}

// ---------------- kernel 3: merge 4 split-KV partials (512 blocks, 32 rows each) ----------------
__global__ __launch_bounds__(256) void merge(const unsigned short* __restrict__ po,
                                             const float* __restrict__ pml,
                                             float* __restrict__ out){
  const int mblk = blockIdx.x;
  const int b = mblk & 7, q32 = mblk >> 3;
  const int tokbase = b*SEQ + q32*32;
  const int tid = threadIdx.x;
  const int row = tokbase + (tid >> 3);
  const int c0 = (tid & 7) * 16;

  f32x4 ml0 = *reinterpret_cast<const f32x4*>(pml + (size_t)row*8);
  f32x4 ml1 = *reinterpret_cast<const f32x4*>(pml + (size_t)row*8 + 4);
  float m[4] = {ml0[0], ml0[2], ml1[0], ml1[2]};
  float l[4] = {ml0[1], ml0[3], ml1[1], ml1[3]};
  float M = fmaxf(fmaxf(m[0], m[1]), fmaxf(m[2], m[3]));
  float a[4], L = 0.f;
  #pragma unroll
  for (int qq=0;qq<4;qq++){ a[qq] = exp2f(m[qq] - M); L += a[qq]*l[qq]; }
  float inv = 1.f / L;
  #pragma unroll
  for (int qq=0;qq<4;qq++) a[qq] *= inv;

  float r[16];
  #pragma unroll
  for (int j=0;j<16;j++) r[j] = 0.f;
  #pragma unroll
  for (int qq=0;qq<4;qq++){
    const unsigned short* pp = po + (size_t)(qq*TOK + row)*128 + c0;
    bf16x8 v0 = *reinterpret_cast<const bf16x8*>(pp);
    bf16x8 v1 = *reinterpret_cast<const bf16x8*>(pp + 8);
    #pragma unroll
    for (int j=0;j<8;j++){
      r[j]   += bf2f((unsigned short)v0[j]) * a[qq];
      r[8+j] += bf2f((unsigned short)v1[j]) * a[qq];
    }
  }
  float* op = out + (size_t)row*256 + c0;
  #pragma unroll
  for (int k=0;k<4;k++){
    float4 rv = {r[k*4+0], r[k*4+1], r[k*4+2], r[k*4+3]};
    *reinterpret_cast<float4*>(op + k*4) = rv;
  }
}

extern "C" void kernel_launch(void* const* d_in, const int* in_sizes, int n_in,
                              void* d_out, int out_size, void* d_ws, size_t ws_size,
                              hipStream_t stream){
  (void)in_sizes; (void)n_in; (void)out_size; (void)ws_size;
  const float* q   = (const float*)d_in[0];
  const float* adj = (const float*)d_in[3];
  const float* W1  = (const float*)d_in[4];
  const float* Wq  = (const float*)d_in[5];
  const float* Wk  = (const float*)d_in[6];
  const float* Wv  = (const float*)d_in[7];
  float* out = (float*)d_out;

  unsigned short* qh = (unsigned short*)d_ws;        // 4 MB
  unsigned short* kh = qh + (size_t)TOK*DIM;         // 4 MB (pre-swizzled rows)
  unsigned short* vh = kh + (size_t)TOK*DIM;         // 4 MB (transposed per batch)
  unsigned short* wt = vh + (size_t)TOK*DIM;         // 128 KB
  unsigned short* po = wt + 4*128*128;               // 16.8 MB (4 x bf16 partial O)
  float*          pml = (float*)(po + (size_t)4*TOK*DIM);  // 512 KB

  prep_w<<<16,  256, 0, stream>>>(W1, Wq, Wk, Wv, wt);
  proj  <<<256, 512, 0, stream>>>(q, wt, out, qh, kh, vh);
  attn  <<<512, 256, 0, stream>>>(qh, kh, vh, adj, po, pml);
  merge <<<512, 256, 0, stream>>>(po, pml, out);
}